// Round 11
// baseline (6304.801 us; speedup 1.0000x reference)
//
#include <hip/hip_runtime.h>
#include <hip/hip_bf16.h>

__device__ __forceinline__ float ssp_f(float x) {
    // shifted softplus: softplus(x) - log(2), numerically stable
    return fmaxf(x, 0.f) + log1pf(__expf(-fabsf(x))) - 0.6931471805599453f;
}

// ---------------- float dtype sniffer ----------------------------------------
__global__ void sniff_kernel(const unsigned int* __restrict__ raw, int* __restrict__ flag)
{
    __shared__ int cnt[256];
    const int t = threadIdx.x;
    unsigned int w = raw[t];
    unsigned int e = (w >> 7) & 0xFFu;
    cnt[t] = (e >= 100u && e <= 135u) ? 1 : 0;
    __syncthreads();
    for (int s = 128; s > 0; s >>= 1) {
        if (t < s) cnt[t] += cnt[t + s];
        __syncthreads();
    }
    if (t == 0) *flag = (cnt[0] >= 160) ? 1 : 0;   // 1 = floats are bf16
}

// ---------------- int width sniffer -------------------------------------------
__global__ void sniff_int_kernel(const unsigned int* __restrict__ z, int* __restrict__ iflag)
{
    __shared__ int cnt[128];
    const int t = threadIdx.x;
    cnt[t] = (z[2 * t + 1] == 0u) ? 1 : 0;
    __syncthreads();
    for (int s = 64; s > 0; s >>= 1) {
        if (t < s) cnt[t] += cnt[t + s];
        __syncthreads();
    }
    if (t == 0) *iflag = (cnt[0] >= 126) ? 1 : 0;  // 1 = ints are int64
}

// ---------------- per-tensor convert float -> f32 -----------------------------
__global__ __launch_bounds__(256) void convert_kernel(
    const void* __restrict__ src, float* __restrict__ dst, int n,
    const int* __restrict__ flag)
{
    int i = blockIdx.x * 256 + threadIdx.x;
    if (i >= n) return;
    if (*flag) dst[i] = __bfloat162float(((const __hip_bfloat16*)src)[i]);
    else       dst[i] = ((const float*)src)[i];
}

__global__ __launch_bounds__(256) void convert_int_kernel(
    const void* __restrict__ src, int* __restrict__ dst, int n,
    const int* __restrict__ iflag)
{
    int i = blockIdx.x * 256 + threadIdx.x;
    if (i >= n) return;
    if (*iflag) dst[i] = (int)(((const long long*)src)[i]);
    else        dst[i] = ((const int*)src)[i];
}

// ---------------- node embedding gather ---------------------------------------
__global__ __launch_bounds__(256) void embed_kernel(
    const int* __restrict__ z, const float* __restrict__ embf,
    float* __restrict__ h, int NH)
{
    int idx = blockIdx.x * 256 + threadIdx.x;
    if (idx >= NH) return;
    h[idx] = embf[z[idx >> 7] * 128 + (idx & 127)];
}

// ---------------- node GEMM [N,128]@[128,128], one block per row --------------
template<int MODE>
__global__ __launch_bounds__(128) void node_gemm_simple(
    const float* __restrict__ in, const float* __restrict__ W,
    const float* __restrict__ bias, float* __restrict__ out)
{
    __shared__ float row_s[128];
    const int n = blockIdx.x;
    const int c = threadIdx.x;
    row_s[c] = in[(long)n * 128 + c];
    __syncthreads();
    float a = (MODE != 0) ? bias[c] : 0.f;
    #pragma unroll 8
    for (int k = 0; k < 128; ++k)
        a = fmaf(row_s[k], W[k * 128 + c], a);
    if (MODE == 1) a = ssp_f(a);
    if (MODE == 2) a += out[(long)n * 128 + c];
    out[(long)n * 128 + c] = a;
}

// ---------------- fused edge features + MLP + gather-mul + scatter-add --------
__global__ __launch_bounds__(128) void edge_simple(
    const float* __restrict__ posf,
    const int* __restrict__ row, const int* __restrict__ col,
    const float* __restrict__ eattrf,
    const float* __restrict__ w1, const float* __restrict__ b1,
    const float* __restrict__ w2, const float* __restrict__ b2,
    const float* __restrict__ xh, float* __restrict__ agg,
    int NB, int F50, float delta, float coeff)
{
    __shared__ float ea_s[64];
    __shared__ float t_s[128];
    __shared__ float ew_sh, C_sh;
    __shared__ int   r_sh, c_sh;

    const int e = blockIdx.x;
    const int c = threadIdx.x;

    if (c == 0) {
        int r = row[e], cc = col[e];
        r_sh = r; c_sh = cc;
        float dx = posf[r*3+0] - posf[cc*3+0];
        float dy = posf[r*3+1] - posf[cc*3+1];
        float dz = posf[r*3+2] - posf[cc*3+2];
        float ew = sqrtf(dx*dx + dy*dy + dz*dz);
        ew_sh = ew;
        C_sh  = 0.5f * (cosf(ew * 0.3141592653589793f) + 1.0f);  // pi/10
    }
    __syncthreads();
    if (c < NB) {
        ea_s[c] = eattrf[(long)e * NB + c];
    } else if (c < F50) {
        float d = ew_sh - (float)(c - NB) * delta;
        ea_s[c] = __expf(coeff * d * d);
    }
    __syncthreads();

    float a = b1[c];
    for (int k = 0; k < F50; ++k)
        a = fmaf(ea_s[k], w1[k * 128 + c], a);
    t_s[c] = ssp_f(a);
    __syncthreads();

    float w = b2[c];
    #pragma unroll 8
    for (int k = 0; k < 128; ++k)
        w = fmaf(t_s[k], w2[k * 128 + c], w);
    w *= C_sh;

    atomicAdd(&agg[(long)c_sh * 128 + c], w * xh[(long)r_sh * 128 + c]);
}

// ---------------- readout: one block (128 thr) per node -----------------------
__global__ __launch_bounds__(128) void readout_simple(
    const float* __restrict__ h,
    const float* __restrict__ o1w, const float* __restrict__ o1b,
    const float* __restrict__ o2w, const float* __restrict__ o2b,
    const int* __restrict__ batch, float* __restrict__ accb)
{
    __shared__ float hr[128];
    __shared__ float vv[64];
    const int n = blockIdx.x;
    const int t = threadIdx.x;
    hr[t] = h[(long)n * 128 + t];
    __syncthreads();
    if (t < 64) {
        float a = o1b[t];
        #pragma unroll 8
        for (int k = 0; k < 128; ++k)
            a = fmaf(hr[k], o1w[k * 64 + t], a);
        vv[t] = ssp_f(a) * o2w[t];
    }
    __syncthreads();
    if (t < 32) vv[t] += vv[t + 32];
    __syncthreads();
    if (t < 16) vv[t] += vv[t + 16];
    __syncthreads();
    if (t < 8)  vv[t] += vv[t + 8];
    __syncthreads();
    if (t < 4)  vv[t] += vv[t + 4];
    __syncthreads();
    if (t < 2)  vv[t] += vv[t + 2];
    __syncthreads();
    if (t == 0) atomicAdd(&accb[batch[n]], vv[0] + vv[1] + o2b[0]);
}

// FIX (round 11): output is FLOAT32 (reference returns jnp.float32; the
// checker's "(bf16...)" label is a hardcoded f-string). Write 16 f32 values.
__global__ void finalize_kernel(const float* __restrict__ accb,
                                float* __restrict__ out, int B)
{
    int t = blockIdx.x * 256 + threadIdx.x;
    if (t < B) out[t] = accb[t];
}

// ---------------- launch -------------------------------------------------------
extern "C" void kernel_launch(void* const* d_in, const int* in_sizes, int n_in,
                              void* d_out, int out_size, void* d_ws, size_t ws_size,
                              hipStream_t stream)
{
    const int N   = in_sizes[0];
    const int E   = in_sizes[3] / 2;
    const int B   = out_size;
    const int H   = 128;
    const int L   = in_sizes[7] / H;
    const int NB  = in_sizes[4] / E;
    const int F50 = in_sizes[6] / (L * H);
    const int NGS = F50 - NB;
    const float delta = 10.0f / (float)(NGS - 1);
    const float coeff = -0.5f / (delta * delta);

    const int fidx[16] = {1, 4, 5, 6, 7, 8, 9, 10, 11, 12, 13, 14, 15, 16, 17, 18};
    long foff[17]; foff[0] = 0;
    for (int i = 0; i < 16; ++i) foff[i + 1] = foff[i] + in_sizes[fidx[i]];

    float* F = (float*)d_ws;
    long base = (foff[16] + 3) & ~3L;
    float* h    = F + base;
    float* xh   = h + (long)N * H;
    float* agg  = xh + (long)N * H;
    float* accb = agg + (long)N * H;
    int*   flag  = (int*)(accb + ((B + 3) & ~3));
    int*   iflag = flag + 1;
    int*   zi     = flag + 4;
    int*   batchi = zi + N;
    int*   eidxi  = batchi + N;

    sniff_kernel<<<1, 256, 0, stream>>>((const unsigned int*)d_in[5], flag);
    sniff_int_kernel<<<1, 128, 0, stream>>>((const unsigned int*)d_in[0], iflag);

    for (int i = 0; i < 16; ++i) {
        int n = in_sizes[fidx[i]];
        convert_kernel<<<(n + 255) / 256, 256, 0, stream>>>(d_in[fidx[i]], F + foff[i], n, flag);
    }
    convert_int_kernel<<<(N + 255) / 256, 256, 0, stream>>>(d_in[0], zi, N, iflag);
    convert_int_kernel<<<(N + 255) / 256, 256, 0, stream>>>(d_in[2], batchi, N, iflag);
    convert_int_kernel<<<(2 * E + 255) / 256, 256, 0, stream>>>(d_in[3], eidxi, 2 * E, iflag);

    const float* posf   = F + foff[0];
    const float* eattrf = F + foff[1];
    const float* embf   = F + foff[2];
    const float* w1   = F + foff[3];  const float* b1   = F + foff[4];
    const float* w2   = F + foff[5];  const float* b2   = F + foff[6];
    const float* cf1  = F + foff[7];  const float* cf2  = F + foff[8];
    const float* cf2b = F + foff[9];  const float* lin  = F + foff[10];
    const float* linb = F + foff[11]; const float* o1   = F + foff[12];
    const float* o1b  = F + foff[13]; const float* o2   = F + foff[14];
    const float* o2b  = F + foff[15];

    embed_kernel<<<(N * H + 255) / 256, 256, 0, stream>>>(zi, embf, h, N * H);
    hipMemsetAsync(accb, 0, (size_t)B * sizeof(float), stream);

    for (int l = 0; l < L; ++l) {
        hipMemsetAsync(agg, 0, (size_t)N * H * sizeof(float), stream);
        node_gemm_simple<0><<<N, 128, 0, stream>>>(h, cf1 + (long)l * H * H, nullptr, xh);
        edge_simple<<<E, 128, 0, stream>>>(
            posf, eidxi, eidxi + E, eattrf,
            w1 + (long)l * F50 * H, b1 + (long)l * H,
            w2 + (long)l * H * H,  b2 + (long)l * H,
            xh, agg, NB, F50, delta, coeff);
        node_gemm_simple<1><<<N, 128, 0, stream>>>(agg, cf2 + (long)l * H * H, cf2b + (long)l * H, xh);
        node_gemm_simple<2><<<N, 128, 0, stream>>>(xh, lin + (long)l * H * H, linb + (long)l * H, h);
    }

    readout_simple<<<N, 128, 0, stream>>>(h, o1, o1b, o2, o2b, batchi, accb);
    finalize_kernel<<<(B + 255) / 256, 256, 0, stream>>>(accb, (float*)d_out, B);
}

// Round 12
// 4336.713 us; speedup vs baseline: 1.4538x; 1.4538x over previous
//
#include <hip/hip_runtime.h>
#include <hip/hip_bf16.h>

__device__ __forceinline__ float ssp_f(float x) {
    return fmaxf(x, 0.f) + log1pf(__expf(-fabsf(x))) - 0.6931471805599453f;
}

// ---------------- float dtype sniffer ----------------------------------------
__global__ void sniff_kernel(const unsigned int* __restrict__ raw, int* __restrict__ flag)
{
    __shared__ int cnt[256];
    const int t = threadIdx.x;
    unsigned int w = raw[t];
    unsigned int e = (w >> 7) & 0xFFu;
    cnt[t] = (e >= 100u && e <= 135u) ? 1 : 0;
    __syncthreads();
    for (int s = 128; s > 0; s >>= 1) {
        if (t < s) cnt[t] += cnt[t + s];
        __syncthreads();
    }
    if (t == 0) *flag = (cnt[0] >= 160) ? 1 : 0;   // 1 = floats are bf16
}

// ---------------- int width sniffer -------------------------------------------
__global__ void sniff_int_kernel(const unsigned int* __restrict__ z, int* __restrict__ iflag)
{
    __shared__ int cnt[128];
    const int t = threadIdx.x;
    cnt[t] = (z[2 * t + 1] == 0u) ? 1 : 0;
    __syncthreads();
    for (int s = 64; s > 0; s >>= 1) {
        if (t < s) cnt[t] += cnt[t + s];
        __syncthreads();
    }
    if (t == 0) *iflag = (cnt[0] >= 126) ? 1 : 0;  // 1 = ints are int64
}

// ---------------- converts -----------------------------------------------------
__global__ __launch_bounds__(256) void convert_kernel(
    const void* __restrict__ src, float* __restrict__ dst, int n,
    const int* __restrict__ flag)
{
    int i = blockIdx.x * 256 + threadIdx.x;
    if (i >= n) return;
    if (*flag) dst[i] = __bfloat162float(((const __hip_bfloat16*)src)[i]);
    else       dst[i] = ((const float*)src)[i];
}

__global__ __launch_bounds__(256) void convert_int_kernel(
    const void* __restrict__ src, int* __restrict__ dst, int n,
    const int* __restrict__ iflag)
{
    int i = blockIdx.x * 256 + threadIdx.x;
    if (i >= n) return;
    if (*iflag) dst[i] = (int)(((const long long*)src)[i]);
    else        dst[i] = ((const int*)src)[i];
}

// ---------------- node embedding gather ---------------------------------------
__global__ __launch_bounds__(256) void embed_kernel(
    const int* __restrict__ z, const float* __restrict__ embf,
    float* __restrict__ h, int NH)
{
    int idx = blockIdx.x * 256 + threadIdx.x;
    if (idx >= NH) return;
    h[idx] = embf[z[idx >> 7] * 128 + (idx & 127)];
}

// ---------------- tiled node GEMM [N,128]@[128,128] ---------------------------
// 32 rows/block, 256 threads, 4x4 register tile per thread.
// MODE 0: out = in@W ; MODE 1: out = ssp(in@W+b) ; MODE 2: out += in@W+b
template<int MODE>
__global__ __launch_bounds__(256) void node_gemm_tiled(
    const float* __restrict__ in, const float* __restrict__ W,
    const float* __restrict__ bias, float* __restrict__ out, int N)
{
    __shared__ float in_s[32][128];
    const int t = threadIdx.x;
    const long n0 = (long)blockIdx.x * 32;
    for (int i = t; i < 32 * 128; i += 256) {
        long n = n0 + (i >> 7);
        in_s[i >> 7][i & 127] = (n < N) ? in[n * 128 + (i & 127)] : 0.f;
    }
    __syncthreads();
    const int j = t & 31, sub = t >> 5;
    const int c4 = j * 4, rb = sub * 4;
    float acc[4][4];
    float4 bv = make_float4(0.f, 0.f, 0.f, 0.f);
    if (MODE != 0) bv = *(const float4*)(bias + c4);
    #pragma unroll
    for (int i = 0; i < 4; ++i) { acc[i][0]=bv.x; acc[i][1]=bv.y; acc[i][2]=bv.z; acc[i][3]=bv.w; }
    #pragma unroll 4
    for (int k = 0; k < 128; ++k) {
        const float4 wv = *(const float4*)(W + k * 128 + c4);
        #pragma unroll
        for (int i = 0; i < 4; ++i) {
            const float a = in_s[rb + i][k];
            acc[i][0] += a * wv.x; acc[i][1] += a * wv.y;
            acc[i][2] += a * wv.z; acc[i][3] += a * wv.w;
        }
    }
    #pragma unroll
    for (int i = 0; i < 4; ++i) {
        long n = n0 + rb + i;
        if (n >= N) continue;
        float4 o;
        if (MODE == 1) {
            o.x = ssp_f(acc[i][0]); o.y = ssp_f(acc[i][1]);
            o.z = ssp_f(acc[i][2]); o.w = ssp_f(acc[i][3]);
        } else {
            o.x = acc[i][0]; o.y = acc[i][1]; o.z = acc[i][2]; o.w = acc[i][3];
        }
        if (MODE == 2) {
            float4 p = *(const float4*)(out + n * 128 + c4);
            o.x += p.x; o.y += p.y; o.z += p.z; o.w += p.w;
        }
        *(float4*)(out + n * 128 + c4) = o;
    }
}

// ---------------- tiled fused edge kernel -------------------------------------
// 32 edges/block, 256 threads, 4x4 register tile: 16 FMA per float4 weight load.
__global__ __launch_bounds__(256) void edge_tiled(
    const float* __restrict__ posf,
    const int* __restrict__ row, const int* __restrict__ col,
    const float* __restrict__ eattrf,
    const float* __restrict__ w1, const float* __restrict__ b1,
    const float* __restrict__ w2, const float* __restrict__ b2,
    const float* __restrict__ xh, float* __restrict__ agg,
    int E, int NB, int F50, float delta, float coeff)
{
    __shared__ float ea_s[32][52];   // F50<=50 used; 52 stride breaks aliasing
    __shared__ float t_s[32][128];
    __shared__ int   row_s[32];
    __shared__ int   col_s[32];
    __shared__ float C_s[32];
    __shared__ float ew_s[32];

    const int t = threadIdx.x;
    const long e0 = (long)blockIdx.x * 32;

    if (t < 32) {
        long e = e0 + t; if (e >= E) e = E - 1;
        const int r = row[e], c = col[e];
        row_s[t] = r; col_s[t] = c;
        float dx = posf[r*3+0] - posf[c*3+0];
        float dy = posf[r*3+1] - posf[c*3+1];
        float dz = posf[r*3+2] - posf[c*3+2];
        float ew = sqrtf(dx*dx + dy*dy + dz*dz);
        ew_s[t] = ew;
        C_s[t]  = 0.5f * (cosf(ew * 0.3141592653589793f) + 1.0f);  // pi/10
        for (int q = 0; q < NB; ++q)
            ea_s[t][q] = eattrf[e * NB + q];
    }
    __syncthreads();
    {
        const int NGS = F50 - NB;
        for (int i = t; i < 32 * NGS; i += 256) {
            const int e = i / NGS, g = i - e * NGS;
            const float d = ew_s[e] - (float)g * delta;
            ea_s[e][NB + g] = __expf(coeff * d * d);
        }
    }
    __syncthreads();

    const int j   = t & 31;
    const int sub = t >> 5;
    const int c4  = j * 4;
    const int eb  = sub * 4;

    float acc[4][4];
    // ---- GEMM1: [32,F50] @ [F50,128] + b1 -> ssp -> t_s ----
    {
        const float4 bv = *(const float4*)(b1 + c4);
        #pragma unroll
        for (int i = 0; i < 4; ++i) { acc[i][0]=bv.x; acc[i][1]=bv.y; acc[i][2]=bv.z; acc[i][3]=bv.w; }
        for (int k = 0; k < F50; ++k) {
            const float4 wv = *(const float4*)(w1 + k * 128 + c4);
            #pragma unroll
            for (int i = 0; i < 4; ++i) {
                const float a = ea_s[eb + i][k];
                acc[i][0] += a * wv.x; acc[i][1] += a * wv.y;
                acc[i][2] += a * wv.z; acc[i][3] += a * wv.w;
            }
        }
        #pragma unroll
        for (int i = 0; i < 4; ++i) {
            float4 o;
            o.x = ssp_f(acc[i][0]); o.y = ssp_f(acc[i][1]);
            o.z = ssp_f(acc[i][2]); o.w = ssp_f(acc[i][3]);
            *(float4*)&t_s[eb + i][c4] = o;
        }
    }
    __syncthreads();

    // ---- GEMM2: [32,128] @ [128,128] + b2 ----
    {
        const float4 bv = *(const float4*)(b2 + c4);
        #pragma unroll
        for (int i = 0; i < 4; ++i) { acc[i][0]=bv.x; acc[i][1]=bv.y; acc[i][2]=bv.z; acc[i][3]=bv.w; }
        #pragma unroll 4
        for (int k = 0; k < 128; ++k) {
            const float4 wv = *(const float4*)(w2 + k * 128 + c4);
            #pragma unroll
            for (int i = 0; i < 4; ++i) {
                const float a = t_s[eb + i][k];
                acc[i][0] += a * wv.x; acc[i][1] += a * wv.y;
                acc[i][2] += a * wv.z; acc[i][3] += a * wv.w;
            }
        }
    }

    // ---- epilogue: W*C, gather xh[row], scatter-add agg[col] ----
    #pragma unroll
    for (int i = 0; i < 4; ++i) {
        const int e = eb + i;
        if (e0 + e >= E) continue;
        const float Ce = C_s[e];
        const float4 xv = *(const float4*)(xh + (long)row_s[e] * 128 + c4);
        float* ag = agg + (long)col_s[e] * 128 + c4;
        atomicAdd(ag + 0, acc[i][0] * Ce * xv.x);
        atomicAdd(ag + 1, acc[i][1] * Ce * xv.y);
        atomicAdd(ag + 2, acc[i][2] * Ce * xv.z);
        atomicAdd(ag + 3, acc[i][3] * Ce * xv.w);
    }
}

// ---------------- readout: one block (128 thr) per node -----------------------
__global__ __launch_bounds__(128) void readout_simple(
    const float* __restrict__ h,
    const float* __restrict__ o1w, const float* __restrict__ o1b,
    const float* __restrict__ o2w, const float* __restrict__ o2b,
    const int* __restrict__ batch, float* __restrict__ accb)
{
    __shared__ float hr[128];
    __shared__ float vv[64];
    const int n = blockIdx.x;
    const int t = threadIdx.x;
    hr[t] = h[(long)n * 128 + t];
    __syncthreads();
    if (t < 64) {
        float a = o1b[t];
        #pragma unroll 8
        for (int k = 0; k < 128; ++k)
            a = fmaf(hr[k], o1w[k * 64 + t], a);
        vv[t] = ssp_f(a) * o2w[t];
    }
    __syncthreads();
    if (t < 32) vv[t] += vv[t + 32];
    __syncthreads();
    if (t < 16) vv[t] += vv[t + 16];
    __syncthreads();
    if (t < 8)  vv[t] += vv[t + 8];
    __syncthreads();
    if (t < 4)  vv[t] += vv[t + 4];
    __syncthreads();
    if (t < 2)  vv[t] += vv[t + 2];
    __syncthreads();
    if (t == 0) atomicAdd(&accb[batch[n]], vv[0] + vv[1] + o2b[0]);
}

// output is FLOAT32 (verified round 11)
__global__ void finalize_kernel(const float* __restrict__ accb,
                                float* __restrict__ out, int B)
{
    int t = blockIdx.x * 256 + threadIdx.x;
    if (t < B) out[t] = accb[t];
}

// ---------------- launch -------------------------------------------------------
extern "C" void kernel_launch(void* const* d_in, const int* in_sizes, int n_in,
                              void* d_out, int out_size, void* d_ws, size_t ws_size,
                              hipStream_t stream)
{
    const int N   = in_sizes[0];
    const int E   = in_sizes[3] / 2;
    const int B   = out_size;
    const int H   = 128;
    const int L   = in_sizes[7] / H;
    const int NB  = in_sizes[4] / E;
    const int F50 = in_sizes[6] / (L * H);
    const int NGS = F50 - NB;
    const float delta = 10.0f / (float)(NGS - 1);
    const float coeff = -0.5f / (delta * delta);

    const int fidx[16] = {1, 4, 5, 6, 7, 8, 9, 10, 11, 12, 13, 14, 15, 16, 17, 18};
    long foff[17]; foff[0] = 0;
    for (int i = 0; i < 16; ++i) foff[i + 1] = foff[i] + in_sizes[fidx[i]];

    float* F = (float*)d_ws;
    long base = (foff[16] + 3) & ~3L;
    float* h    = F + base;
    float* xh   = h + (long)N * H;
    float* agg  = xh + (long)N * H;
    float* accb = agg + (long)N * H;
    int*   flag  = (int*)(accb + ((B + 3) & ~3));
    int*   iflag = flag + 1;
    int*   zi     = flag + 4;
    int*   batchi = zi + N;
    int*   eidxi  = batchi + N;

    sniff_kernel<<<1, 256, 0, stream>>>((const unsigned int*)d_in[5], flag);
    sniff_int_kernel<<<1, 128, 0, stream>>>((const unsigned int*)d_in[0], iflag);

    for (int i = 0; i < 16; ++i) {
        int n = in_sizes[fidx[i]];
        convert_kernel<<<(n + 255) / 256, 256, 0, stream>>>(d_in[fidx[i]], F + foff[i], n, flag);
    }
    convert_int_kernel<<<(N + 255) / 256, 256, 0, stream>>>(d_in[0], zi, N, iflag);
    convert_int_kernel<<<(N + 255) / 256, 256, 0, stream>>>(d_in[2], batchi, N, iflag);
    convert_int_kernel<<<(2 * E + 255) / 256, 256, 0, stream>>>(d_in[3], eidxi, 2 * E, iflag);

    const float* posf   = F + foff[0];
    const float* eattrf = F + foff[1];
    const float* embf   = F + foff[2];
    const float* w1   = F + foff[3];  const float* b1   = F + foff[4];
    const float* w2   = F + foff[5];  const float* b2   = F + foff[6];
    const float* cf1  = F + foff[7];  const float* cf2  = F + foff[8];
    const float* cf2b = F + foff[9];  const float* lin  = F + foff[10];
    const float* linb = F + foff[11]; const float* o1   = F + foff[12];
    const float* o1b  = F + foff[13]; const float* o2   = F + foff[14];
    const float* o2b  = F + foff[15];

    embed_kernel<<<(N * H + 255) / 256, 256, 0, stream>>>(zi, embf, h, N * H);
    hipMemsetAsync(accb, 0, (size_t)B * sizeof(float), stream);

    const int ngemm = (N + 31) / 32;
    const int nedge = (E + 31) / 32;
    for (int l = 0; l < L; ++l) {
        hipMemsetAsync(agg, 0, (size_t)N * H * sizeof(float), stream);
        node_gemm_tiled<0><<<ngemm, 256, 0, stream>>>(h, cf1 + (long)l * H * H, nullptr, xh, N);
        edge_tiled<<<nedge, 256, 0, stream>>>(
            posf, eidxi, eidxi + E, eattrf,
            w1 + (long)l * F50 * H, b1 + (long)l * H,
            w2 + (long)l * H * H,  b2 + (long)l * H,
            xh, agg, E, NB, F50, delta, coeff);
        node_gemm_tiled<1><<<ngemm, 256, 0, stream>>>(agg, cf2 + (long)l * H * H, cf2b + (long)l * H, xh, N);
        node_gemm_tiled<2><<<ngemm, 256, 0, stream>>>(xh, lin + (long)l * H * H, linb + (long)l * H, h, N);
    }

    readout_simple<<<N, 128, 0, stream>>>(h, o1, o1b, o2, o2b, batchi, accb);
    finalize_kernel<<<(B + 255) / 256, 256, 0, stream>>>(accb, (float*)d_out, B);
}